// Round 1
// baseline (163.944 us; speedup 1.0000x reference)
//
#include <hip/hip_runtime.h>

#define T_ 4096   // B*S tokens
#define D_ 1024
#define E_ 8
#define MT 64
#define NT 128
#define KT 64     // k per LDS stage (was 32): halves K-steps & barriers
#define ROWS_ (MT + NT)

typedef __attribute__((ext_vector_type(8))) short short8;
typedef __attribute__((ext_vector_type(4))) float floatx4;

__device__ __forceinline__ unsigned short f2bf(float f) {
    union { float ff; unsigned int i; } v; v.ff = f;
    unsigned int i = v.i + 0x7fffu + ((v.i >> 16) & 1u);   // RNE
    return (unsigned short)(i >> 16);
}
__device__ __forceinline__ short8 pack8(float4 a, float4 b) {
    short8 r;
    r[0] = (short)f2bf(a.x); r[1] = (short)f2bf(a.y);
    r[2] = (short)f2bf(a.z); r[3] = (short)f2bf(a.w);
    r[4] = (short)f2bf(b.x); r[5] = (short)f2bf(b.y);
    r[6] = (short)f2bf(b.z); r[7] = (short)f2bf(b.w);
    return r;
}
__device__ __forceinline__ void glds16(const void* g, void* l) {
    __builtin_amdgcn_global_load_lds(
        (const __attribute__((address_space(1))) unsigned int*)g,
        (__attribute__((address_space(3))) unsigned int*)l, 16, 0, 0);
}

// ---- Router + fused bucketize (global atomics) + x/ew f32->bf16 ----
__global__ __launch_bounds__(256) void moe_router(
    const float* __restrict__ x,
    const float* __restrict__ rw,
    const float* __restrict__ rb,
    const float* __restrict__ ew,
    unsigned short* __restrict__ xbf,
    unsigned short* __restrict__ ewbf,
    float* __restrict__ wts,
    int*   __restrict__ counts,
    int*   __restrict__ bucket)
{
    const int wave = threadIdx.x >> 6;
    const int lane = threadIdx.x & 63;
    const int tok  = blockIdx.x * 4 + wave;

    const float* xp = x + (size_t)tok * D_ + lane * 16;
    float4 xv[4];
    #pragma unroll
    for (int i = 0; i < 4; i++) xv[i] = *(const float4*)(xp + i * 4);

    unsigned short* xd = xbf + (size_t)tok * D_ + lane * 16;
    *(short8*)(xd)     = pack8(xv[0], xv[1]);
    *(short8*)(xd + 8) = pack8(xv[2], xv[3]);

    float xf[16];
    #pragma unroll
    for (int i = 0; i < 4; i++) {
        xf[i*4+0] = xv[i].x; xf[i*4+1] = xv[i].y;
        xf[i*4+2] = xv[i].z; xf[i*4+3] = xv[i].w;
    }

    float acc[E_];
    #pragma unroll
    for (int e = 0; e < E_; e++) {
        const float* wp = rw + e * D_ + lane * 16;
        float s = 0.f;
        #pragma unroll
        for (int i = 0; i < 4; i++) {
            float4 v = *(const float4*)(wp + i * 4);
            s += xf[i*4+0]*v.x + xf[i*4+1]*v.y + xf[i*4+2]*v.z + xf[i*4+3]*v.w;
        }
        acc[e] = s;
    }
    #pragma unroll
    for (int off = 32; off > 0; off >>= 1) {
        #pragma unroll
        for (int e = 0; e < E_; e++)
            acc[e] += __shfl_xor(acc[e], off, 64);
    }

    float lmax = -3.4e38f; int idx = 0;
    #pragma unroll
    for (int e = 0; e < E_; e++) {
        acc[e] += rb[e];
        if (acc[e] > lmax) { lmax = acc[e]; idx = e; }   // strict > = first max (numpy argmax)
    }
    float sum = 0.f;
    #pragma unroll
    for (int e = 0; e < E_; e++) sum += expf(acc[e] - lmax);

    if (lane == 0) {
        wts[tok] = 1.0f / sum;
        int pos = atomicAdd(&counts[idx], 1);   // device-scope, 8 hot words
        bucket[idx * T_ + pos] = tok;           // order nondeterministic: OK, per-token output order-independent
    }

    // ew convert: block slice of 8192 elems
    const size_t base = (size_t)blockIdx.x * 8192 + threadIdx.x * 8;
    #pragma unroll
    for (int j = 0; j < 4; j++) {
        size_t o = base + (size_t)j * 2048;
        float4 a = *(const float4*)(ew + o);
        float4 b = *(const float4*)(ew + o + 4);
        *(short8*)(ewbf + o) = pack8(a, b);
    }
}

// ---- Grouped GEMM: 64x128 tile, double-buffered KT=64 stage, 1 barrier/K-step ----
__global__ __launch_bounds__(256) void moe_gemm(
    const unsigned short* __restrict__ xbf,
    const unsigned short* __restrict__ ewbf,
    const float* __restrict__ eb,
    const float* __restrict__ wts,
    const int*  __restrict__ counts,
    const int*  __restrict__ bucket,
    float* __restrict__ out)
{
    const int bid = blockIdx.x;
    const int e   = bid & 7;            // consecutive bids -> XCD RR pins expert to XCD (L2 locality)
    const int nb  = (bid >> 3) & 7;
    const int mt  = bid >> 6;           // 0..31
    const int cnt = counts[e];
    if (mt * MT >= cnt) return;
    const int n0 = nb * NT;

    __shared__ int   toks[MT];
    __shared__ float twt[MT];
    __shared__ __align__(16) unsigned short Stage[2][ROWS_ * KT];  // 2 x 24 KB: rows 0-63 = A, 64-191 = B

    const int tid  = threadIdx.x;
    const int lane = tid & 63;
    const int w    = tid >> 6;
    const int wm   = w >> 1;            // 0/1: rows wm*32
    const int wn   = w & 1;             // 0/1: cols wn*64
    const int l16  = lane & 15;
    const int kq   = lane >> 4;         // 0..3

    // staging: 24 glds16 per stage, 6 per wave; instr j covers rows 8j..8j+7 (8 slots x 16B per row)
    int srow[6]; int sgc[6]; int soff[6];
    #pragma unroll
    for (int i = 0; i < 6; i++) {
        int j    = w * 6 + i;
        int row  = j * 8 + (lane >> 3);
        int slot = lane & 7;
        srow[i] = row;
        sgc[i]  = slot ^ (row & 7);      // XOR swizzle: global k-chunk stored in this slot
        soff[i] = j * 512;               // LDS short offset of instr j's 1KB block (+ lane*16B implicit)
    }
    const size_t ebase = (size_t)e << 20;

    for (int m0 = mt * MT; m0 < cnt; m0 += 32 * MT) {
        const int valid = min(MT, cnt - m0);
        __syncthreads();                 // protect toks/twt across m0 iterations
        if (tid < MT) {
            int r = (tid < valid) ? tid : 0;
            int t = bucket[e * T_ + m0 + r];
            toks[tid] = t;
            twt[tid]  = wts[t];
        }
        __syncthreads();

        const unsigned short* src[6];
        #pragma unroll
        for (int i = 0; i < 6; i++) {
            int row = srow[i];
            src[i] = (row < MT)
                ? xbf + (size_t)toks[row] * D_ + sgc[i] * 8
                : ewbf + ebase + (size_t)(n0 + row - MT) * D_ + sgc[i] * 8;
        }

        floatx4 acc[2][4];
        #pragma unroll
        for (int mi = 0; mi < 2; mi++)
            #pragma unroll
            for (int ni = 0; ni < 4; ni++) acc[mi][ni] = (floatx4){0,0,0,0};

        // prologue: stage K-tile 0 into buf 0
        #pragma unroll
        for (int i = 0; i < 6; i++) glds16(src[i], &Stage[0][soff[i]]);
        __syncthreads();                 // vmcnt(0) drain: buf0 ready for all waves

        int cur = 0;
        for (int k0 = 0; k0 < D_; k0 += KT) {
            // T3 minimum 2-phase: issue next tile's loads BEFORE computing current
            if (k0 + KT < D_) {
                #pragma unroll
                for (int i = 0; i < 6; i++) glds16(src[i] + k0 + KT, &Stage[cur ^ 1][soff[i]]);
            }

            short8 a[2][2], b[4][2];
            #pragma unroll
            for (int ks = 0; ks < 2; ks++) {
                #pragma unroll
                for (int mi = 0; mi < 2; mi++) {
                    int ar = wm * 32 + mi * 16 + l16;
                    a[mi][ks] = *(const short8*)&Stage[cur][ar * KT + (((ks << 2) + kq) ^ (ar & 7)) * 8];
                }
                #pragma unroll
                for (int ni = 0; ni < 4; ni++) {
                    int br = MT + wn * 64 + ni * 16 + l16;
                    b[ni][ks] = *(const short8*)&Stage[cur][br * KT + (((ks << 2) + kq) ^ (br & 7)) * 8];
                }
            }
            #pragma unroll
            for (int ks = 0; ks < 2; ks++)
                #pragma unroll
                for (int mi = 0; mi < 2; mi++)
                    #pragma unroll
                    for (int ni = 0; ni < 4; ni++)
                        acc[mi][ni] = __builtin_amdgcn_mfma_f32_16x16x32_bf16(a[mi][ks], b[ni][ks], acc[mi][ni], 0, 0, 0);

            __syncthreads();             // single barrier/K-step: drains next-tile vmcnt AFTER ds_read+MFMA cover
            cur ^= 1;
        }

        // epilogue: C/D layout col=lane&15, row=(lane>>4)*4+reg
        const int rq = kq * 4;
        #pragma unroll
        for (int ni = 0; ni < 4; ni++) {
            const int col  = n0 + wn * 64 + ni * 16 + l16;
            const float bias = eb[e * D_ + col];
            #pragma unroll
            for (int mi = 0; mi < 2; mi++) {
                #pragma unroll
                for (int r = 0; r < 4; r++) {
                    int row = wm * 32 + mi * 16 + rq + r;
                    if (row < valid)
                        out[(size_t)toks[row] * D_ + col] = (acc[mi][ni][r] + bias) * twt[row];
                }
            }
        }
    }
}

extern "C" void kernel_launch(void* const* d_in, const int* in_sizes, int n_in,
                              void* d_out, int out_size, void* d_ws, size_t ws_size,
                              hipStream_t stream) {
    (void)in_sizes; (void)n_in; (void)out_size; (void)ws_size;
    const float* x  = (const float*)d_in[0];
    const float* rw = (const float*)d_in[1];
    const float* rb = (const float*)d_in[2];
    const float* ew = (const float*)d_in[3];
    const float* eb = (const float*)d_in[4];
    float* out = (float*)d_out;

    // ws carve: xbf 8MB | ewbf 16MB | wts | counts | bucket
    unsigned short* xbf  = (unsigned short*)d_ws;
    unsigned short* ewbf = xbf + (size_t)T_ * D_;
    float* wts    = (float*)(ewbf + (size_t)E_ * D_ * D_);
    int*   counts = (int*)(wts + T_);
    int*   bucket = counts + E_;

    hipMemsetAsync(counts, 0, E_ * sizeof(int), stream);   // 32 B, graph-capturable memset node
    moe_router<<<dim3(T_ / 4), dim3(256), 0, stream>>>(x, rw, rb, ew, xbf, ewbf, wts, counts, bucket);
    moe_gemm<<<dim3(2048), dim3(256), 0, stream>>>(xbf, ewbf, eb, wts, counts, bucket, out);
}

// Round 2
// 126.438 us; speedup vs baseline: 1.2966x; 1.2966x over previous
//
#include <hip/hip_runtime.h>

#define T_ 4096   // B*S tokens
#define D_ 1024
#define E_ 8
#define MT 64
#define NT 128
#define KT 64     // k per LDS stage
#define ROWS_ (MT + NT)
#define RB_ 1024  // router blocks; blocks >= RB_ do ew conversion

typedef __attribute__((ext_vector_type(8))) short short8;
typedef __attribute__((ext_vector_type(4))) float floatx4;

__device__ __forceinline__ unsigned short f2bf(float f) {
    union { float ff; unsigned int i; } v; v.ff = f;
    unsigned int i = v.i + 0x7fffu + ((v.i >> 16) & 1u);   // RNE
    return (unsigned short)(i >> 16);
}
__device__ __forceinline__ short8 pack8(float4 a, float4 b) {
    short8 r;
    r[0] = (short)f2bf(a.x); r[1] = (short)f2bf(a.y);
    r[2] = (short)f2bf(a.z); r[3] = (short)f2bf(a.w);
    r[4] = (short)f2bf(b.x); r[5] = (short)f2bf(b.y);
    r[6] = (short)f2bf(b.z); r[7] = (short)f2bf(b.w);
    return r;
}
__device__ __forceinline__ void glds16(const void* g, void* l) {
    __builtin_amdgcn_global_load_lds(
        (const __attribute__((address_space(1))) unsigned int*)g,
        (__attribute__((address_space(3))) unsigned int*)l, 16, 0, 0);
}

// ---- Block-specialized: router (blocks 0..1023) + ew f32->bf16 stream (blocks 1024..3071) ----
__global__ __launch_bounds__(256) void moe_router(
    const float* __restrict__ x,
    const float* __restrict__ rw,
    const float* __restrict__ rb,
    const float* __restrict__ ew,
    unsigned short* __restrict__ xbf,
    unsigned short* __restrict__ ewbf,
    float* __restrict__ wts,
    int*   __restrict__ top1)
{
    const int bid = blockIdx.x;
    if (bid >= RB_) {
        // pure streaming conversion: 2048 blocks x 4096 elems, runs CONCURRENTLY with router blocks
        const size_t base = (size_t)(bid - RB_) * 4096 + threadIdx.x * 8;
        #pragma unroll
        for (int j = 0; j < 2; j++) {
            size_t o = base + (size_t)j * 2048;
            float4 a = *(const float4*)(ew + o);
            float4 b = *(const float4*)(ew + o + 4);
            *(short8*)(ewbf + o) = pack8(a, b);
        }
        return;
    }

    const int wave = threadIdx.x >> 6;
    const int lane = threadIdx.x & 63;
    const int tok  = bid * 4 + wave;

    const float* xp = x + (size_t)tok * D_ + lane * 16;
    float4 xv[4];
    #pragma unroll
    for (int i = 0; i < 4; i++) xv[i] = *(const float4*)(xp + i * 4);

    unsigned short* xd = xbf + (size_t)tok * D_ + lane * 16;
    *(short8*)(xd)     = pack8(xv[0], xv[1]);
    *(short8*)(xd + 8) = pack8(xv[2], xv[3]);

    float xf[16];
    #pragma unroll
    for (int i = 0; i < 4; i++) {
        xf[i*4+0] = xv[i].x; xf[i*4+1] = xv[i].y;
        xf[i*4+2] = xv[i].z; xf[i*4+3] = xv[i].w;
    }

    float acc[E_];
    #pragma unroll
    for (int e = 0; e < E_; e++) {
        const float* wp = rw + e * D_ + lane * 16;
        float s = 0.f;
        #pragma unroll
        for (int i = 0; i < 4; i++) {
            float4 v = *(const float4*)(wp + i * 4);
            s += xf[i*4+0]*v.x + xf[i*4+1]*v.y + xf[i*4+2]*v.z + xf[i*4+3]*v.w;
        }
        acc[e] = s;
    }
    #pragma unroll
    for (int off = 32; off > 0; off >>= 1) {
        #pragma unroll
        for (int e = 0; e < E_; e++)
            acc[e] += __shfl_xor(acc[e], off, 64);
    }

    float lmax = -3.4e38f; int idx = 0;
    #pragma unroll
    for (int e = 0; e < E_; e++) {
        acc[e] += rb[e];
        if (acc[e] > lmax) { lmax = acc[e]; idx = e; }   // strict > = first max (numpy argmax)
    }
    float sum = 0.f;
    #pragma unroll
    for (int e = 0; e < E_; e++) sum += expf(acc[e] - lmax);

    if (lane == 0) {
        wts[tok]  = 1.0f / sum;
        top1[tok] = idx;
    }
}

// ---- Bucketize: single block, LDS atomics (no cross-XCD contention) ----
__global__ __launch_bounds__(1024) void moe_bucketize(
    const int* __restrict__ top1,
    int* __restrict__ counts,
    int* __restrict__ bucket)
{
    __shared__ int c[E_];
    if (threadIdx.x < E_) c[threadIdx.x] = 0;
    __syncthreads();
    for (int t = threadIdx.x; t < T_; t += 1024) {
        int e = top1[t];
        int pos = atomicAdd(&c[e], 1);
        bucket[e * T_ + pos] = t;
    }
    __syncthreads();
    if (threadIdx.x < E_) counts[threadIdx.x] = c[threadIdx.x];
}

// ---- Grouped GEMM: 64x128 tile, double-buffered KT=64 stage, 1 barrier/K-step ----
__global__ __launch_bounds__(256) void moe_gemm(
    const unsigned short* __restrict__ xbf,
    const unsigned short* __restrict__ ewbf,
    const float* __restrict__ eb,
    const float* __restrict__ wts,
    const int*  __restrict__ counts,
    const int*  __restrict__ bucket,
    float* __restrict__ out)
{
    const int bid = blockIdx.x;
    const int e   = bid & 7;            // consecutive bids -> XCD RR pins expert to XCD (L2 locality)
    const int nb  = (bid >> 3) & 7;
    const int mt  = bid >> 6;           // 0..31
    const int cnt = counts[e];
    if (mt * MT >= cnt) return;
    const int n0 = nb * NT;

    __shared__ int   toks[MT];
    __shared__ float twt[MT];
    __shared__ __align__(16) unsigned short Stage[2][ROWS_ * KT];  // 2 x 24 KB: rows 0-63 = A, 64-191 = B

    const int tid  = threadIdx.x;
    const int lane = tid & 63;
    const int w    = tid >> 6;
    const int wm   = w >> 1;            // 0/1: rows wm*32
    const int wn   = w & 1;             // 0/1: cols wn*64
    const int l16  = lane & 15;
    const int kq   = lane >> 4;         // 0..3

    // staging: 24 glds16 per stage, 6 per wave; instr j covers rows 8j..8j+7 (8 slots x 16B per row)
    int srow[6]; int sgc[6]; int soff[6];
    #pragma unroll
    for (int i = 0; i < 6; i++) {
        int j    = w * 6 + i;
        int row  = j * 8 + (lane >> 3);
        int slot = lane & 7;
        srow[i] = row;
        sgc[i]  = slot ^ (row & 7);      // XOR swizzle: global k-chunk stored in this slot
        soff[i] = j * 512;               // LDS short offset of instr j's 1KB block (+ lane*16B implicit)
    }
    const size_t ebase = (size_t)e << 20;

    for (int m0 = mt * MT; m0 < cnt; m0 += 32 * MT) {
        const int valid = min(MT, cnt - m0);
        __syncthreads();                 // protect toks/twt across m0 iterations
        if (tid < MT) {
            int r = (tid < valid) ? tid : 0;
            int t = bucket[e * T_ + m0 + r];
            toks[tid] = t;
            twt[tid]  = wts[t];
        }
        __syncthreads();

        const unsigned short* src[6];
        #pragma unroll
        for (int i = 0; i < 6; i++) {
            int row = srow[i];
            src[i] = (row < MT)
                ? xbf + (size_t)toks[row] * D_ + sgc[i] * 8
                : ewbf + ebase + (size_t)(n0 + row - MT) * D_ + sgc[i] * 8;
        }

        floatx4 acc[2][4];
        #pragma unroll
        for (int mi = 0; mi < 2; mi++)
            #pragma unroll
            for (int ni = 0; ni < 4; ni++) acc[mi][ni] = (floatx4){0,0,0,0};

        // prologue: stage K-tile 0 into buf 0
        #pragma unroll
        for (int i = 0; i < 6; i++) glds16(src[i], &Stage[0][soff[i]]);
        __syncthreads();                 // buf0 ready for all waves

        int cur = 0;
        for (int k0 = 0; k0 < D_; k0 += KT) {
            // T3 minimum 2-phase: issue next tile's loads BEFORE computing current
            if (k0 + KT < D_) {
                #pragma unroll
                for (int i = 0; i < 6; i++) glds16(src[i] + k0 + KT, &Stage[cur ^ 1][soff[i]]);
            }

            short8 a[2][2], b[4][2];
            #pragma unroll
            for (int ks = 0; ks < 2; ks++) {
                #pragma unroll
                for (int mi = 0; mi < 2; mi++) {
                    int ar = wm * 32 + mi * 16 + l16;
                    a[mi][ks] = *(const short8*)&Stage[cur][ar * KT + (((ks << 2) + kq) ^ (ar & 7)) * 8];
                }
                #pragma unroll
                for (int ni = 0; ni < 4; ni++) {
                    int br = MT + wn * 64 + ni * 16 + l16;
                    b[ni][ks] = *(const short8*)&Stage[cur][br * KT + (((ks << 2) + kq) ^ (br & 7)) * 8];
                }
            }
            #pragma unroll
            for (int ks = 0; ks < 2; ks++)
                #pragma unroll
                for (int mi = 0; mi < 2; mi++)
                    #pragma unroll
                    for (int ni = 0; ni < 4; ni++)
                        acc[mi][ni] = __builtin_amdgcn_mfma_f32_16x16x32_bf16(a[mi][ks], b[ni][ks], acc[mi][ni], 0, 0, 0);

            __syncthreads();             // drains next-tile vmcnt AFTER ds_read+MFMA cover
            cur ^= 1;
        }

        // epilogue: C/D layout col=lane&15, row=(lane>>4)*4+reg
        const int rq = kq * 4;
        #pragma unroll
        for (int ni = 0; ni < 4; ni++) {
            const int col  = n0 + wn * 64 + ni * 16 + l16;
            const float bias = eb[e * D_ + col];
            #pragma unroll
            for (int mi = 0; mi < 2; mi++) {
                #pragma unroll
                for (int r = 0; r < 4; r++) {
                    int row = wm * 32 + mi * 16 + rq + r;
                    if (row < valid)
                        out[(size_t)toks[row] * D_ + col] = (acc[mi][ni][r] + bias) * twt[row];
                }
            }
        }
    }
}

extern "C" void kernel_launch(void* const* d_in, const int* in_sizes, int n_in,
                              void* d_out, int out_size, void* d_ws, size_t ws_size,
                              hipStream_t stream) {
    (void)in_sizes; (void)n_in; (void)out_size; (void)ws_size;
    const float* x  = (const float*)d_in[0];
    const float* rw = (const float*)d_in[1];
    const float* rb = (const float*)d_in[2];
    const float* ew = (const float*)d_in[3];
    const float* eb = (const float*)d_in[4];
    float* out = (float*)d_out;

    // ws carve: xbf 8MB | ewbf 16MB | wts | top1 | counts | bucket
    unsigned short* xbf  = (unsigned short*)d_ws;
    unsigned short* ewbf = xbf + (size_t)T_ * D_;
    float* wts    = (float*)(ewbf + (size_t)E_ * D_ * D_);
    int*   top1   = (int*)(wts + T_);
    int*   counts = top1 + T_;
    int*   bucket = counts + E_;

    moe_router<<<dim3(RB_ + 2048), dim3(256), 0, stream>>>(x, rw, rb, ew, xbf, ewbf, wts, top1);
    moe_bucketize<<<dim3(1), dim3(1024), 0, stream>>>(top1, counts, bucket);
    moe_gemm<<<dim3(2048), dim3(256), 0, stream>>>(xbf, ewbf, eb, wts, counts, bucket, out);
}